// Round 1
// baseline (3905.127 us; speedup 1.0000x reference)
//
#include <hip/hip_runtime.h>
#include <cmath>

// ---- problem constants ----
#define NBS 8
#define NC 20
#define NFH 480
#define NFW 640
#define NHS 240
#define NWS 320
#define NM 480
#define NPIX (NM * NM)   // 230400
#define NVR 100
#define NNZ 48
#define NFEAT 17         // 1 occupancy + 16 semantic

// ---- d_out layout (float element offsets) ----
// out = [translated (8,20,480,480) | map_pred | map_pred_stair | poses (8,3)]
constexpr long long T_OFF    = 0LL;
constexpr long long P_OFF    = 36864000LL;   // 8*20*230400
constexpr long long S_OFF    = 73728000LL;
constexpr long long POSE_OFF = 110592000LL;
// big voxel scratch lives in P+S regions (dead until final kernels overwrite)
constexpr long long VOX_OFF  = P_OFF;
constexpr long long VOX_N    = 65280000LL;   // 8*17*100*100*48
// small scratch in S-region tail (after voxel end, before pose region)
constexpr long long SC_OFF   = 102144000LL;  // == VOX_OFF + VOX_N
constexpr long long SMAP_N   = 1520000LL;    // 8*19*100*100
constexpr long long PAR_OFF  = SC_OFF + SMAP_N;  // 64 floats of params
// copies in P-region head (voxels dead by then); consumed before P is written
constexpr long long SMAP2_OFF = P_OFF;
constexpr long long PAR2_OFF  = SMAP2_OFF + SMAP_N;
constexpr long long TS_OFF    = PAR2_OFF + 64;   // translated_stair ch0, 8*230400

__device__ __forceinline__ float clamp01(float x) {
    return fminf(fmaxf(x, 0.0f), 1.0f);
}

// ---------------- K1: poses + affine params ----------------
__global__ void k_pose(const float* __restrict__ pose_obs,
                       const float* __restrict__ poses_last,
                       float* __restrict__ outp) {
    int b = threadIdx.x;
    if (b >= NBS) return;
    float* pose_out = outp + POSE_OFF;
    float* par = outp + PAR_OFF;
    const float DEGf = 57.29577951308232f;
    float tr = poses_last[b * 3 + 2] / DEGf;
    float s_tr = sinf(tr), c_tr = cosf(tr);
    float ny = poses_last[b * 3 + 1] + pose_obs[b * 3 + 0] * s_tr + pose_obs[b * 3 + 1] * c_tr;
    float nx = poses_last[b * 3 + 0] + pose_obs[b * 3 + 0] * c_tr - pose_obs[b * 3 + 1] * s_tr;
    float no = poses_last[b * 3 + 2] + pose_obs[b * 3 + 2] * DEGf;
    no = fmodf(no - 180.0f, 360.0f) + 180.0f;
    no = fmodf(no + 180.0f, 360.0f) - 180.0f;
    pose_out[b * 3 + 0] = nx;
    pose_out[b * 3 + 1] = ny;
    pose_out[b * 3 + 2] = no;
    float stx = -((nx * 100.0f) / 5.0f - 240.0f) / 240.0f;
    float sty = -((ny * 100.0f) / 5.0f - 240.0f) / 240.0f;
    float stt = ((90.0f - no) * 3.14159265358979323846f) / 180.0f;
    par[b * 4 + 0] = cosf(stt);
    par[b * 4 + 1] = sinf(stt);
    par[b * 4 + 2] = stx;
    par[b * 4 + 3] = sty;
    if (b == 0) {
        int sy = (int)((ny * 100.0f) / 5.0f);   // truncation matches astype(int32)
        int sx = (int)((nx * 100.0f) / 5.0f);
        sy = min(max(sy, 30), NM - 31);
        sx = min(max(sx, 30), NM - 31);
        par[32] = (float)sy;
        par[33] = (float)sx;
    }
}

// ---------------- K2: voxel splat (trilinear scatter-add) ----------------
__global__ void k_splat(const float* __restrict__ obs,
                        const float* __restrict__ eve,
                        float* __restrict__ vox, float camf) {
    int tid = blockIdx.x * blockDim.x + threadIdx.x;
    if (tid >= NBS * NHS * NWS) return;
    int b = tid / (NHS * NWS);
    int p = tid % (NHS * NWS);
    int iy = p / NWS, ix = p % NWS;
    const float* ob = obs + (long long)b * NC * NFH * NFW;
    float depth = ob[(3LL * NFH + 2 * iy) * NFW + 2 * ix];
    float th = eve[b] * 0.017453292519943295f;
    float ct = cosf(th), st = sinf(th);
    float X = ((float)(2 * ix) - 319.5f) * depth / camf;
    float Z = ((float)(479 - 2 * iy) - 239.5f) * depth / camf;
    float Yr = ct * depth - st * Z;
    float Zr = st * depth + ct * Z + 88.0f;
    float Xs = X + 250.0f;
    float cx = ((Xs / 5.0f) - 50.0f) / 100.0f * 2.0f;
    float cy = ((Yr / 5.0f) - 50.0f) / 100.0f * 2.0f;
    float cz = ((Zr / 5.0f) - 16.0f) / 48.0f * 2.0f;
    float posx = (cx * 100.0f) / 2.0f + 50.0f;
    float posy = (cy * 100.0f) / 2.0f + 50.0f;
    float posz = (cz * 48.0f) / 2.0f + 24.0f;
    float fx = floorf(posx), fy = floorf(posy), fz = floorf(posz);
    float wx[2], wy[2], wz[2];
    int ixp[2], iyp[2], izp[2];
#pragma unroll
    for (int k = 0; k < 2; ++k) {
        float px = fx + (float)k;
        bool sx_ = (px > 0.0f) && (px < 100.0f);
        wx[k] = sx_ ? (1.0f - fabsf(posx - px)) : 0.0f;
        ixp[k] = sx_ ? (int)px : 0;
        float py = fy + (float)k;
        bool sy_ = (py > 0.0f) && (py < 100.0f);
        wy[k] = sy_ ? (1.0f - fabsf(posy - py)) : 0.0f;
        iyp[k] = sy_ ? (int)py : 0;
        float pz = fz + (float)k;
        bool sz_ = (pz > 0.0f) && (pz < 48.0f);
        wz[k] = sz_ ? (1.0f - fabsf(posz - pz)) : 0.0f;
        izp[k] = sz_ ? (int)pz : 0;
    }
    if ((wx[0] + wx[1]) == 0.0f || (wy[0] + wy[1]) == 0.0f || (wz[0] + wz[1]) == 0.0f)
        return;  // all 8 corners dead
    float sem[16];
#pragma unroll
    for (int k = 0; k < 16; ++k) {
        const float* q = ob + ((long long)(4 + k) * NFH + 2 * iy) * NFW + 2 * ix;
        sem[k] = (q[0] + q[1] + q[NFW] + q[NFW + 1]) * 0.25f;
    }
    float* vb = vox + (long long)b * NFEAT * 480000;
#pragma unroll
    for (int a = 0; a < 2; ++a)
#pragma unroll
        for (int c2 = 0; c2 < 2; ++c2)
#pragma unroll
            for (int d2 = 0; d2 < 2; ++d2) {
                float w = wx[a] * wy[c2] * wz[d2];
                if (w == 0.0f) continue;
                int idx = (ixp[a] * 100 + iyp[c2]) * 48 + izp[d2];
                atomicAdd(vb + idx, w);  // feature 0 (ones)
#pragma unroll
                for (int k = 0; k < 16; ++k)
                    atomicAdd(vb + (long long)(1 + k) * 480000 + idx, sem[k] * w);
            }
}

// ---------------- K3: round + z-projections -> small maps ----------------
// smap channels: 0=fp_map, 1=fp_exp, 2=fp_stair, 3..18 = cat0..15
__global__ void k_proj(const float* __restrict__ vox, float* __restrict__ smap) {
    int tid = blockIdx.x * blockDim.x + threadIdx.x;
    if (tid >= NBS * NVR * NVR) return;
    int b = tid / (NVR * NVR);
    int ij = tid % (NVR * NVR);
    int i = ij / NVR, j = ij % NVR;  // i = row (cy dim), j = col (cx dim)
    const float* vb = vox + (long long)b * NFEAT * 480000 + (long long)(j * NVR + i) * NNZ;
    float* sm = smap + (long long)b * 19 * 10000;
    {
        float all = 0.0f, ah = 0.0f, stp = 0.0f;
        for (int z = 0; z < NNZ; ++z) {
            float r = rintf(vb[z]);
            all += r;
            if (z >= 13 && z < 35) ah += r;
            if (z >= 20 && z < 25) stp += r;
        }
        sm[ij] = clamp01(ah);             // fp_map   (MAP_T = 1)
        sm[10000 + ij] = clamp01(all);    // fp_exp   (EXP_T = 1)
        sm[20000 + ij] = clamp01(stp);    // fp_stair
    }
    for (int f = 1; f < NFEAT; ++f) {
        const float* v = vb + (long long)f * 480000;
        float ah = 0.0f;
        for (int z = 13; z < 35; ++z) ah += rintf(v[z]);
        sm[(2 + f) * 10000 + ij] = clamp01(ah / 5.0f);  // CAT_T = 5
    }
}

// ---------------- K3b: relocate small scratch out of S region ----------------
__global__ void k_copy(const float* __restrict__ src, float* __restrict__ dst, int n) {
    int tid = blockIdx.x * blockDim.x + threadIdx.x;
    if (tid < n) dst[tid] = src[tid];
}

// ---------------- K4: fused rotate+translate grid_sample ----------------
__global__ void k_translate(float* __restrict__ outp,
                            const float* __restrict__ smap,
                            const float* __restrict__ par,
                            float* __restrict__ tstair) {
    int tid = blockIdx.x * blockDim.x + threadIdx.x;
    if (tid >= NBS * NPIX) return;
    int b = tid / NPIX;
    int ij = tid % NPIX;
    int i = ij / NM, j = ij % NM;
    float c = par[b * 4 + 0], s = par[b * 4 + 1];
    float stx = par[b * 4 + 2], sty = par[b * 4 + 3];
    float gx = (((float)j + 0.5f) * 2.0f) / 480.0f - 1.0f;
    float gy = (((float)i + 0.5f) * 2.0f) / 480.0f - 1.0f;
    float px = ((gx + stx) + 1.0f) * 479.0f / 2.0f;
    float py = ((gy + sty) + 1.0f) * 479.0f / 2.0f;
    float x0 = floorf(px), y0 = floorf(py);
    float wx1 = px - x0, wx0 = 1.0f - wx1;
    float wy1 = py - y0, wy0 = 1.0f - wy1;
    int offs[16];
    float wts[16];
    int nt = 0;
#pragma unroll
    for (int t = 0; t < 4; ++t) {  // outer taps in reference gather order
        int ox = t & 1, oy = t >> 1;
        float xo = x0 + (float)ox, yo = y0 + (float)oy;
        if (!(xo >= 0.0f && xo < 480.0f && yo >= 0.0f && yo < 480.0f)) continue;
        float wo = (ox ? wx1 : wx0) * (oy ? wy1 : wy0);
        int ixo = (int)xo, iyo = (int)yo;
        float gx2 = (((float)ixo + 0.5f) * 2.0f) / 480.0f - 1.0f;
        float gy2 = (((float)iyo + 0.5f) * 2.0f) / 480.0f - 1.0f;
        float rx = c * gx2 - s * gy2;
        float ry = s * gx2 + c * gy2;
        float qx = (rx + 1.0f) * 479.0f / 2.0f;
        float qy = (ry + 1.0f) * 479.0f / 2.0f;
        float xq0 = floorf(qx), yq0 = floorf(qy);
        float u1 = qx - xq0, u0 = 1.0f - u1;
        float v1 = qy - yq0, v0 = 1.0f - v1;
#pragma unroll
        for (int t2 = 0; t2 < 4; ++t2) {
            int ax = t2 & 1, ay = t2 >> 1;
            float xa = xq0 + (float)ax, ya = yq0 + (float)ay;
            // agent_view nonzero window: rows [240,340), cols [190,290)
            if (xa >= 190.0f && xa < 290.0f && ya >= 240.0f && ya < 340.0f) {
                float w = wo * ((ax ? u1 : u0) * (ay ? v1 : v0));
                if (w != 0.0f) {
                    offs[nt] = ((int)ya - 240) * 100 + ((int)xa - 190);
                    wts[nt] = w;
                    ++nt;
                }
            }
        }
    }
    float* To = outp + T_OFF;
    long long obase = (long long)b * NC * NPIX + ij;
    if (nt == 0) {  // fast path: entirely outside agent-view support
#pragma unroll
        for (int ch = 0; ch < NC; ++ch) To[obase + (long long)ch * NPIX] = 0.0f;
        tstair[(long long)b * NPIX + ij] = 0.0f;
        return;
    }
    const float* sm = smap + (long long)b * 19 * 10000;
    float a0 = 0.0f, a1 = 0.0f, as_ = 0.0f;
    float cat[16];
#pragma unroll
    for (int k = 0; k < 16; ++k) cat[k] = 0.0f;
    for (int t = 0; t < nt; ++t) {
        float w = wts[t];
        int o = offs[t];
        a0 += w * sm[o];
        a1 += w * sm[10000 + o];
        as_ += w * sm[20000 + o];
#pragma unroll
        for (int k = 0; k < 16; ++k) cat[k] += w * sm[(3 + k) * 10000 + o];
    }
    To[obase] = a0;
    To[obase + (long long)NPIX] = a1;
    To[obase + 2LL * NPIX] = 0.0f;
    To[obase + 3LL * NPIX] = 0.0f;
#pragma unroll
    for (int k = 0; k < 16; ++k) To[obase + (long long)(4 + k) * NPIX] = cat[k];
    tstair[(long long)b * NPIX + ij] = as_;
}

// ---------------- K5: map_pred_stair (writes full S region) ----------------
__global__ void k_stair(const float* __restrict__ T, const float* __restrict__ tstair,
                        const float* __restrict__ par, const float* __restrict__ maps_last,
                        const float* __restrict__ eve, float* __restrict__ outS) {
    int tid = blockIdx.x * blockDim.x + threadIdx.x;
    if (tid >= NBS * NPIX) return;
    int b = tid / NPIX;
    int ij = tid % NPIX;
    int i = ij / NM, j = ij % NM;
    bool eve0 = (eve[b] == 0.0f);
    const float* Tb = T + (long long)b * NC * NPIX;
    float ts0 = tstair[(long long)b * NPIX + ij];
    float t1 = Tb[(long long)NPIX + ij];
    if (b == 0) {
        float dy = (float)i - par[32] + 0.5f;
        float dx = (float)j - par[33] + 0.5f;
        float mask = (dy * dy + dx * dx <= 900.0f) ? 1.0f : 0.0f;
        ts0 *= mask;
        t1 *= mask;
    }
    bool flag = (t1 - ts0) > 0.8f;
    const float* ml = maps_last + (long long)b * NC * NPIX;
    long long obase = (long long)b * NC * NPIX + ij;
#pragma unroll
    for (int ch = 0; ch < NC; ++ch) {
        float tch = (ch == 0) ? ts0 : (ch == 1) ? t1 : Tb[(long long)ch * NPIX + ij];
        float m3 = fmaxf(ml[(long long)ch * NPIX + ij], tch);
        outS[obase + (long long)ch * NPIX] = (ch == 0 && eve0 && flag) ? 0.0f : m3;
    }
}

// ---------------- K6: map_pred (writes full P region) ----------------
__global__ void k_pred(const float* __restrict__ T, const float* __restrict__ maps_last,
                       const float* __restrict__ eve, float* __restrict__ outP) {
    int tid = blockIdx.x * blockDim.x + threadIdx.x;
    if (tid >= NBS * NPIX) return;
    int b = tid / NPIX;
    int ij = tid % NPIX;
    int i = ij / NM, j = ij % NM;
    const float* Tb = T + (long long)b * NC * NPIX;
    float mp = -INFINITY;  // maxpool3 with -inf padding == max over in-bounds nbrs
#pragma unroll
    for (int di = -1; di <= 1; ++di) {
        int ii = i + di;
        if (ii < 0 || ii >= NM) continue;
#pragma unroll
        for (int dj = -1; dj <= 1; ++dj) {
            int jj = j + dj;
            if (jj < 0 || jj >= NM) continue;
            mp = fmaxf(mp, Tb[(long long)ii * NM + jj]);
        }
    }
    float t1 = Tb[(long long)NPIX + ij];
    bool flag = (t1 - mp) > 0.8f;
    bool eve0 = (eve[b] == 0.0f);
    const float* ml = maps_last + (long long)b * NC * NPIX;
    long long obase = (long long)b * NC * NPIX + ij;
#pragma unroll
    for (int ch = 0; ch < NC; ++ch) {
        float m2 = fmaxf(ml[(long long)ch * NPIX + ij], Tb[(long long)ch * NPIX + ij]);
        outP[obase + (long long)ch * NPIX] = (ch == 0 && eve0 && flag) ? 0.0f : m2;
    }
}

extern "C" void kernel_launch(void* const* d_in, const int* in_sizes, int n_in,
                              void* d_out, int out_size, void* d_ws, size_t ws_size,
                              hipStream_t stream) {
    const float* obs = (const float*)d_in[0];
    const float* pose_obs = (const float*)d_in[1];
    const float* maps_last = (const float*)d_in[2];
    const float* poses_last = (const float*)d_in[3];
    const float* eve = (const float*)d_in[4];
    float* outp = (float*)d_out;

    // host-side exact camera focal constant (matches np.float64 -> f32)
    float camf = (float)(320.0 / tan(39.5 * M_PI / 180.0));

    // zero the voxel scratch (lives inside P+S output regions; dead scratch
    // until k_stair/k_pred overwrite those regions at the end)
    hipMemsetAsync(outp + VOX_OFF, 0, (size_t)VOX_N * sizeof(float), stream);

    k_pose<<<1, 64, 0, stream>>>(pose_obs, poses_last, outp);

    k_splat<<<(NBS * NHS * NWS) / 256, 256, 0, stream>>>(obs, eve, outp + VOX_OFF, camf);

    k_proj<<<(NBS * NVR * NVR + 255) / 256, 256, 0, stream>>>(outp + VOX_OFF, outp + SC_OFF);

    // relocate smaps+params from S-tail to P-head (voxels dead now) so the
    // S-region writer never reads the region it writes
    k_copy<<<(int)((SMAP_N + 64 + 255) / 256), 256, 0, stream>>>(outp + SC_OFF,
                                                                 outp + SMAP2_OFF,
                                                                 (int)(SMAP_N + 64));

    k_translate<<<(NBS * NPIX) / 256, 256, 0, stream>>>(outp, outp + SMAP2_OFF,
                                                        outp + PAR2_OFF, outp + TS_OFF);

    k_stair<<<(NBS * NPIX) / 256, 256, 0, stream>>>(outp + T_OFF, outp + TS_OFF,
                                                    outp + PAR2_OFF, maps_last, eve,
                                                    outp + S_OFF);

    k_pred<<<(NBS * NPIX) / 256, 256, 0, stream>>>(outp + T_OFF, maps_last, eve,
                                                   outp + P_OFF);
}

// Round 2
// 3065.610 us; speedup vs baseline: 1.2739x; 1.2739x over previous
//
#include <hip/hip_runtime.h>
#include <cmath>

// ---- problem constants ----
#define NBS 8
#define NC 20
#define NFH 480
#define NFW 640
#define NHS 240
#define NWS 320
#define NM 480
#define NPIX (NM * NM)   // 230400
#define NVR 100
#define NNZ 48
#define NFEAT 17         // 1 occupancy + 16 semantic
#define ZLO 13
#define ZHI 35
#define COLSTRIDE 400    // 48 occ + 22*16 sem, 1600B (64B-aligned) per column

// ---- d_out layout (float element offsets) ----
// out = [translated (8,20,480,480) | map_pred | map_pred_stair | poses (8,3)]
constexpr long long T_OFF    = 0LL;
constexpr long long P_OFF    = 36864000LL;   // 8*20*230400
constexpr long long S_OFF    = 73728000LL;
constexpr long long POSE_OFF = 110592000LL;
// voxel scratch now fits entirely in the P region (dead until k_pred overwrites)
constexpr long long VOX_OFF  = P_OFF;
constexpr long long VOX_N    = 32000000LL;   // 8*10000*400
// small scratch in P-region tail (still inside P, consumed before k_pred writes)
constexpr long long SMAP_OFF = VOX_OFF + VOX_N;          // 8*19*10000 floats
constexpr long long SMAP_N   = 1520000LL;
constexpr long long PAR_OFF  = SMAP_OFF + SMAP_N;        // 64 floats of params
constexpr long long TS_OFF   = PAR_OFF + 64;             // tstair ch0: 8*230400
// TS end = P_OFF + 35,363,264 < P_OFF + 36,864,000  ✓

__device__ __forceinline__ float clamp01(float x) {
    return fminf(fmaxf(x, 0.0f), 1.0f);
}

// ---------------- K1: poses + affine params ----------------
__global__ void k_pose(const float* __restrict__ pose_obs,
                       const float* __restrict__ poses_last,
                       float* __restrict__ outp) {
    int b = threadIdx.x;
    if (b >= NBS) return;
    float* pose_out = outp + POSE_OFF;
    float* par = outp + PAR_OFF;
    const float DEGf = 57.29577951308232f;
    float tr = poses_last[b * 3 + 2] / DEGf;
    float s_tr = sinf(tr), c_tr = cosf(tr);
    float ny = poses_last[b * 3 + 1] + pose_obs[b * 3 + 0] * s_tr + pose_obs[b * 3 + 1] * c_tr;
    float nx = poses_last[b * 3 + 0] + pose_obs[b * 3 + 0] * c_tr - pose_obs[b * 3 + 1] * s_tr;
    float no = poses_last[b * 3 + 2] + pose_obs[b * 3 + 2] * DEGf;
    no = fmodf(no - 180.0f, 360.0f) + 180.0f;
    no = fmodf(no + 180.0f, 360.0f) - 180.0f;
    pose_out[b * 3 + 0] = nx;
    pose_out[b * 3 + 1] = ny;
    pose_out[b * 3 + 2] = no;
    float stx = -((nx * 100.0f) / 5.0f - 240.0f) / 240.0f;
    float sty = -((ny * 100.0f) / 5.0f - 240.0f) / 240.0f;
    float stt = ((90.0f - no) * 3.14159265358979323846f) / 180.0f;
    par[b * 4 + 0] = cosf(stt);
    par[b * 4 + 1] = sinf(stt);
    par[b * 4 + 2] = stx;
    par[b * 4 + 3] = sty;
    if (b == 0) {
        int sy = (int)((ny * 100.0f) / 5.0f);   // truncation matches astype(int32)
        int sx = (int)((nx * 100.0f) / 5.0f);
        sy = min(max(sy, 30), NM - 31);
        sx = min(max(sx, 30), NM - 31);
        par[32] = (float)sy;
        par[33] = (float)sx;
    }
}

// ---------------- K2: voxel splat (trilinear scatter-add) ----------------
// Feature-interleaved column layout per (b, x*100+y):
//   [0..48)                 occupancy, z
//   [48 + (z-13)*16 + k]    sem feature k, z in [13,35)
// Sem atomics of one corner hit exactly one 64B line (base 1600B-aligned).
__global__ void k_splat(const float* __restrict__ obs,
                        const float* __restrict__ eve,
                        float* __restrict__ vox, float camf) {
    int tid = blockIdx.x * blockDim.x + threadIdx.x;
    if (tid >= NBS * NHS * NWS) return;
    int b = tid / (NHS * NWS);
    int p = tid % (NHS * NWS);
    int iy = p / NWS, ix = p % NWS;
    const float* ob = obs + (long long)b * NC * NFH * NFW;
    float depth = ob[(3LL * NFH + 2 * iy) * NFW + 2 * ix];
    float th = eve[b] * 0.017453292519943295f;
    float ct = cosf(th), st = sinf(th);
    float X = ((float)(2 * ix) - 319.5f) * depth / camf;
    float Z = ((float)(479 - 2 * iy) - 239.5f) * depth / camf;
    float Yr = ct * depth - st * Z;
    float Zr = st * depth + ct * Z + 88.0f;
    float Xs = X + 250.0f;
    float cx = ((Xs / 5.0f) - 50.0f) / 100.0f * 2.0f;
    float cy = ((Yr / 5.0f) - 50.0f) / 100.0f * 2.0f;
    float cz = ((Zr / 5.0f) - 16.0f) / 48.0f * 2.0f;
    float posx = (cx * 100.0f) / 2.0f + 50.0f;
    float posy = (cy * 100.0f) / 2.0f + 50.0f;
    float posz = (cz * 48.0f) / 2.0f + 24.0f;
    float fx = floorf(posx), fy = floorf(posy), fz = floorf(posz);
    float wx[2], wy[2], wz[2];
    int ixp[2], iyp[2], izp[2];
#pragma unroll
    for (int k = 0; k < 2; ++k) {
        float px = fx + (float)k;
        bool sx_ = (px > 0.0f) && (px < 100.0f);
        wx[k] = sx_ ? (1.0f - fabsf(posx - px)) : 0.0f;
        ixp[k] = sx_ ? (int)px : 0;
        float py = fy + (float)k;
        bool sy_ = (py > 0.0f) && (py < 100.0f);
        wy[k] = sy_ ? (1.0f - fabsf(posy - py)) : 0.0f;
        iyp[k] = sy_ ? (int)py : 0;
        float pz = fz + (float)k;
        bool sz_ = (pz > 0.0f) && (pz < 48.0f);
        wz[k] = sz_ ? (1.0f - fabsf(posz - pz)) : 0.0f;
        izp[k] = sz_ ? (int)pz : 0;
    }
    if ((wx[0] + wx[1]) == 0.0f || (wy[0] + wy[1]) == 0.0f || (wz[0] + wz[1]) == 0.0f)
        return;  // all 8 corners dead
    // sem features only needed for corners with z in [13,35)
    bool needSem = false;
#pragma unroll
    for (int k = 0; k < 2; ++k)
        if (wz[k] != 0.0f && izp[k] >= ZLO && izp[k] < ZHI) needSem = true;
    float sem[16];
    if (needSem) {
#pragma unroll
        for (int k = 0; k < 16; ++k) {
            const float* q = ob + ((long long)(4 + k) * NFH + 2 * iy) * NFW + 2 * ix;
            sem[k] = (q[0] + q[1] + q[NFW] + q[NFW + 1]) * 0.25f;
        }
    }
    float* vb = vox + (long long)b * 10000 * COLSTRIDE;
#pragma unroll
    for (int a = 0; a < 2; ++a)
#pragma unroll
        for (int c2 = 0; c2 < 2; ++c2) {
            float wxy = wx[a] * wy[c2];
            if (wxy == 0.0f) continue;
            float* col = vb + (long long)(ixp[a] * 100 + iyp[c2]) * COLSTRIDE;
#pragma unroll
            for (int d2 = 0; d2 < 2; ++d2) {
                float w = wxy * wz[d2];
                if (w == 0.0f) continue;
                int z = izp[d2];
                atomicAdd(col + z, w);  // occupancy
                if (z >= ZLO && z < ZHI) {
                    float* semp = col + 48 + (z - ZLO) * 16;
#pragma unroll
                    for (int k = 0; k < 16; ++k)
                        atomicAdd(semp + k, sem[k] * w);
                }
            }
        }
}

// ---------------- K3: round + z-projections -> small maps ----------------
// smap channels: 0=fp_map, 1=fp_exp, 2=fp_stair, 3..18 = cat0..15
__global__ void k_proj(const float* __restrict__ vox, float* __restrict__ smap) {
    int tid = blockIdx.x * blockDim.x + threadIdx.x;
    if (tid >= NBS * NVR * NVR) return;
    int b = tid / (NVR * NVR);
    int ij = tid % (NVR * NVR);
    int i = ij / NVR, j = ij % NVR;  // i = row (cy dim), j = col (cx dim)
    const float* col = vox + ((long long)b * 10000 + (j * NVR + i)) * COLSTRIDE;
    float* sm = smap + (long long)b * 19 * 10000;
    {
        float all = 0.0f, ah = 0.0f, stp = 0.0f;
        for (int z = 0; z < NNZ; ++z) {
            float r = rintf(col[z]);
            all += r;
            if (z >= ZLO && z < ZHI) ah += r;
            if (z >= 20 && z < 25) stp += r;
        }
        sm[ij] = clamp01(ah);             // fp_map   (MAP_T = 1)
        sm[10000 + ij] = clamp01(all);    // fp_exp   (EXP_T = 1)
        sm[20000 + ij] = clamp01(stp);    // fp_stair
    }
    for (int f = 0; f < 16; ++f) {
        float ah = 0.0f;
        for (int z = ZLO; z < ZHI; ++z) ah += rintf(col[48 + (z - ZLO) * 16 + f]);
        sm[(3 + f) * 10000 + ij] = clamp01(ah / 5.0f);  // CAT_T = 5
    }
}

// ---------------- K4: fused rotate+translate grid_sample ----------------
__global__ void k_translate(float* __restrict__ outp,
                            const float* __restrict__ smap,
                            const float* __restrict__ par,
                            float* __restrict__ tstair) {
    int tid = blockIdx.x * blockDim.x + threadIdx.x;
    if (tid >= NBS * NPIX) return;
    int b = tid / NPIX;
    int ij = tid % NPIX;
    int i = ij / NM, j = ij % NM;
    float c = par[b * 4 + 0], s = par[b * 4 + 1];
    float stx = par[b * 4 + 2], sty = par[b * 4 + 3];
    float gx = (((float)j + 0.5f) * 2.0f) / 480.0f - 1.0f;
    float gy = (((float)i + 0.5f) * 2.0f) / 480.0f - 1.0f;
    float px = ((gx + stx) + 1.0f) * 479.0f / 2.0f;
    float py = ((gy + sty) + 1.0f) * 479.0f / 2.0f;
    float x0 = floorf(px), y0 = floorf(py);
    float wx1 = px - x0, wx0 = 1.0f - wx1;
    float wy1 = py - y0, wy0 = 1.0f - wy1;
    int offs[16];
    float wts[16];
    int nt = 0;
#pragma unroll
    for (int t = 0; t < 4; ++t) {  // outer taps in reference gather order
        int ox = t & 1, oy = t >> 1;
        float xo = x0 + (float)ox, yo = y0 + (float)oy;
        if (!(xo >= 0.0f && xo < 480.0f && yo >= 0.0f && yo < 480.0f)) continue;
        float wo = (ox ? wx1 : wx0) * (oy ? wy1 : wy0);
        int ixo = (int)xo, iyo = (int)yo;
        float gx2 = (((float)ixo + 0.5f) * 2.0f) / 480.0f - 1.0f;
        float gy2 = (((float)iyo + 0.5f) * 2.0f) / 480.0f - 1.0f;
        float rx = c * gx2 - s * gy2;
        float ry = s * gx2 + c * gy2;
        float qx = (rx + 1.0f) * 479.0f / 2.0f;
        float qy = (ry + 1.0f) * 479.0f / 2.0f;
        float xq0 = floorf(qx), yq0 = floorf(qy);
        float u1 = qx - xq0, u0 = 1.0f - u1;
        float v1 = qy - yq0, v0 = 1.0f - v1;
#pragma unroll
        for (int t2 = 0; t2 < 4; ++t2) {
            int ax = t2 & 1, ay = t2 >> 1;
            float xa = xq0 + (float)ax, ya = yq0 + (float)ay;
            // agent_view nonzero window: rows [240,340), cols [190,290)
            if (xa >= 190.0f && xa < 290.0f && ya >= 240.0f && ya < 340.0f) {
                float w = wo * ((ax ? u1 : u0) * (ay ? v1 : v0));
                if (w != 0.0f) {
                    offs[nt] = ((int)ya - 240) * 100 + ((int)xa - 190);
                    wts[nt] = w;
                    ++nt;
                }
            }
        }
    }
    float* To = outp + T_OFF;
    long long obase = (long long)b * NC * NPIX + ij;
    if (nt == 0) {  // fast path: entirely outside agent-view support
#pragma unroll
        for (int ch = 0; ch < NC; ++ch) To[obase + (long long)ch * NPIX] = 0.0f;
        tstair[(long long)b * NPIX + ij] = 0.0f;
        return;
    }
    const float* sm = smap + (long long)b * 19 * 10000;
    float a0 = 0.0f, a1 = 0.0f, as_ = 0.0f;
    float cat[16];
#pragma unroll
    for (int k = 0; k < 16; ++k) cat[k] = 0.0f;
    for (int t = 0; t < nt; ++t) {
        float w = wts[t];
        int o = offs[t];
        a0 += w * sm[o];
        a1 += w * sm[10000 + o];
        as_ += w * sm[20000 + o];
#pragma unroll
        for (int k = 0; k < 16; ++k) cat[k] += w * sm[(3 + k) * 10000 + o];
    }
    To[obase] = a0;
    To[obase + (long long)NPIX] = a1;
    To[obase + 2LL * NPIX] = 0.0f;
    To[obase + 3LL * NPIX] = 0.0f;
#pragma unroll
    for (int k = 0; k < 16; ++k) To[obase + (long long)(4 + k) * NPIX] = cat[k];
    tstair[(long long)b * NPIX + ij] = as_;
}

// ---------------- K5: map_pred_stair (writes full S region) ----------------
__global__ void k_stair(const float* __restrict__ T, const float* __restrict__ tstair,
                        const float* __restrict__ par, const float* __restrict__ maps_last,
                        const float* __restrict__ eve, float* __restrict__ outS) {
    int tid = blockIdx.x * blockDim.x + threadIdx.x;
    if (tid >= NBS * NPIX) return;
    int b = tid / NPIX;
    int ij = tid % NPIX;
    int i = ij / NM, j = ij % NM;
    bool eve0 = (eve[b] == 0.0f);
    const float* Tb = T + (long long)b * NC * NPIX;
    float ts0 = tstair[(long long)b * NPIX + ij];
    float t1 = Tb[(long long)NPIX + ij];
    if (b == 0) {
        float dy = (float)i - par[32] + 0.5f;
        float dx = (float)j - par[33] + 0.5f;
        float mask = (dy * dy + dx * dx <= 900.0f) ? 1.0f : 0.0f;
        ts0 *= mask;
        t1 *= mask;
    }
    bool flag = (t1 - ts0) > 0.8f;
    const float* ml = maps_last + (long long)b * NC * NPIX;
    long long obase = (long long)b * NC * NPIX + ij;
#pragma unroll
    for (int ch = 0; ch < NC; ++ch) {
        float tch = (ch == 0) ? ts0 : (ch == 1) ? t1 : Tb[(long long)ch * NPIX + ij];
        float m3 = fmaxf(ml[(long long)ch * NPIX + ij], tch);
        outS[obase + (long long)ch * NPIX] = (ch == 0 && eve0 && flag) ? 0.0f : m3;
    }
}

// ---------------- K6: map_pred (writes full P region) ----------------
__global__ void k_pred(const float* __restrict__ T, const float* __restrict__ maps_last,
                       const float* __restrict__ eve, float* __restrict__ outP) {
    int tid = blockIdx.x * blockDim.x + threadIdx.x;
    if (tid >= NBS * NPIX) return;
    int b = tid / NPIX;
    int ij = tid % NPIX;
    int i = ij / NM, j = ij % NM;
    const float* Tb = T + (long long)b * NC * NPIX;
    float mp = -INFINITY;  // maxpool3 with -inf padding == max over in-bounds nbrs
#pragma unroll
    for (int di = -1; di <= 1; ++di) {
        int ii = i + di;
        if (ii < 0 || ii >= NM) continue;
#pragma unroll
        for (int dj = -1; dj <= 1; ++dj) {
            int jj = j + dj;
            if (jj < 0 || jj >= NM) continue;
            mp = fmaxf(mp, Tb[(long long)ii * NM + jj]);
        }
    }
    float t1 = Tb[(long long)NPIX + ij];
    bool flag = (t1 - mp) > 0.8f;
    bool eve0 = (eve[b] == 0.0f);
    const float* ml = maps_last + (long long)b * NC * NPIX;
    long long obase = (long long)b * NC * NPIX + ij;
#pragma unroll
    for (int ch = 0; ch < NC; ++ch) {
        float m2 = fmaxf(ml[(long long)ch * NPIX + ij], Tb[(long long)ch * NPIX + ij]);
        outP[obase + (long long)ch * NPIX] = (ch == 0 && eve0 && flag) ? 0.0f : m2;
    }
}

extern "C" void kernel_launch(void* const* d_in, const int* in_sizes, int n_in,
                              void* d_out, int out_size, void* d_ws, size_t ws_size,
                              hipStream_t stream) {
    const float* obs = (const float*)d_in[0];
    const float* pose_obs = (const float*)d_in[1];
    const float* maps_last = (const float*)d_in[2];
    const float* poses_last = (const float*)d_in[3];
    const float* eve = (const float*)d_in[4];
    float* outp = (float*)d_out;

    // host-side exact camera focal constant (matches np.float64 -> f32)
    float camf = (float)(320.0 / tan(39.5 * M_PI / 180.0));

    // zero the voxel scratch (lives in P output region; dead until k_pred)
    hipMemsetAsync(outp + VOX_OFF, 0, (size_t)VOX_N * sizeof(float), stream);

    k_pose<<<1, 64, 0, stream>>>(pose_obs, poses_last, outp);

    k_splat<<<(NBS * NHS * NWS) / 256, 256, 0, stream>>>(obs, eve, outp + VOX_OFF, camf);

    k_proj<<<(NBS * NVR * NVR + 255) / 256, 256, 0, stream>>>(outp + VOX_OFF, outp + SMAP_OFF);

    k_translate<<<(NBS * NPIX) / 256, 256, 0, stream>>>(outp, outp + SMAP_OFF,
                                                        outp + PAR_OFF, outp + TS_OFF);

    k_stair<<<(NBS * NPIX) / 256, 256, 0, stream>>>(outp + T_OFF, outp + TS_OFF,
                                                    outp + PAR_OFF, maps_last, eve,
                                                    outp + S_OFF);

    k_pred<<<(NBS * NPIX) / 256, 256, 0, stream>>>(outp + T_OFF, maps_last, eve,
                                                   outp + P_OFF);
}